// Round 4
// baseline (5688.792 us; speedup 1.0000x reference)
//
#include <hip/hip_runtime.h>
#include <stdint.h>

typedef __bf16 bf16_t;
typedef __bf16 bf16x8 __attribute__((ext_vector_type(8)));
typedef float floatx16 __attribute__((ext_vector_type(16)));
typedef unsigned int u32;
typedef unsigned long long u64;

#define NPROD 64   // Gx producer WGs
#define H1R   8    // h1 ring depth

struct KParams {
  const int* tok;
  const float* emb;
  const float* W1[4]; const float* b1[4];
  const float* W2[4]; const float* b2[4];
  const float* Wd; const float* bd; const float* Wout; const float* bout;
  float* out;
  uint16_t* h1;      // ring: H1R x [64][256] bf16
  uint16_t* h2;      // ring: 2   x [64][256] bf16
  u32* fl0; u32* fl1; u32* pflags;
  float* dstage;     // [64][128] fp32
  bf16_t* w1bf;      // [20][1024][16] fragment-ordered x-weights (bf16)
  float* gx;         // ring: R slabs of [64][1024] fp32
  int R;
};

__device__ __forceinline__ float sigf(float x) { return 1.f / (1.f + __expf(-x)); }
__device__ __forceinline__ float tanhf_fast(float x) { return 1.f - 2.f / (__expf(2.f * x) + 1.f); }

__device__ __forceinline__ u32 pack2(float a, float b) {
  uint16_t x = __builtin_bit_cast(uint16_t, (bf16_t)a);
  uint16_t y = __builtin_bit_cast(uint16_t, (bf16_t)b);
  return ((u32)y << 16) | (u32)x;
}
__device__ __forceinline__ float2 u2f2(u64 v) { union { u64 u; float2 f; } x; x.u = v; return x.f; }
__device__ __forceinline__ bf16x8 mk_frag(u64 lo, u64 hi) {
  union { u64 u[2]; bf16x8 v; } x; x.u[0] = lo; x.u[1] = hi; return x.v;
}

// relaxed agent-scope ops: bypass L1/L2, coherent at LLC
__device__ __forceinline__ u32  ald32(const u32* p) { return __hip_atomic_load(p, __ATOMIC_RELAXED, __HIP_MEMORY_SCOPE_AGENT); }
__device__ __forceinline__ void ast32(u32* p, u32 v) { __hip_atomic_store(p, v, __ATOMIC_RELAXED, __HIP_MEMORY_SCOPE_AGENT); }
__device__ __forceinline__ u64  ald64(const u64* p) { return __hip_atomic_load(p, __ATOMIC_RELAXED, __HIP_MEMORY_SCOPE_AGENT); }

// Wave-parallel dataflow wait: lanes 0-15 check fa[lane]>=na, 16-31 check
// fb[lane-16]>=nb, 32+ check *pc>=nc. Monotonic counters -> race-free.
__device__ __forceinline__ void waitcond(const u32* fa, u32 na, const u32* fb, u32 nb,
                                         const u32* pc, u32 nc) {
  const int lane = threadIdx.x & 63;
  const u32* ap; u32 need;
  if (lane < 16)      { ap = fa + lane;        need = na; }
  else if (lane < 32) { ap = fb + (lane - 16); need = nb; }
  else                { ap = pc;               need = nc; }
  while (!__all(ald32(ap) >= need)) {}
  __atomic_signal_fence(__ATOMIC_ACQUIRE);  // keep later loads after the poll
}

// ---------------- Layer 0: 16 WGs, each owns 16 units (64 gate cols) ----------
__device__ void run_l0(const KParams& p, int sub, float* cst, float* biasl)
{
  const int tid = threadIdx.x;
  const int w = tid >> 6, l = tid & 63, q = l >> 5, lr = l & 31;
  const int mh = w & 1, nh = w >> 1;
  const int arow = mh * 32 + lr;          // batch row for A-frags

  if (tid < 64) biasl[tid] = p.b1[tid >> 4][sub * 16 + (tid & 15)];

  // W1 h-part rows 300..555 -> register B-fragments (reused 512x)
  const int c = nh * 32 + lr;
  const float* Wg = p.W1[c >> 4];
  const int un = sub * 16 + (c & 15);
  bf16x8 wf[16];
#pragma unroll
  for (int s = 0; s < 16; ++s)
#pragma unroll
    for (int j = 0; j < 8; ++j) {
      int k = 16 * s + 8 * q + j;
      wf[s][j] = (bf16_t)Wg[(300 + k) * 256 + un];
    }
  __syncthreads();

  float cs[2][2] = {{0.f, 0.f}, {0.f, 0.f}};

  for (int s = 0; s < 512; ++s) {
    u32 n1 = (s >= 8) ? (u32)(s - 7) : 0u;  // h1-slab reuse guard vs L1 reader
    waitcond(p.fl0, (u32)s, p.fl1, n1, &p.pflags[s], 1u);

    // A-fragments of h1[s-1] direct from LLC (one trip, 32 loads in flight)
    const u64* hp = (const u64*)(p.h1 + ((s + H1R - 1) & (H1R - 1)) * 16384);
    u64 a0[16], a1[16];
#pragma unroll
    for (int s2 = 0; s2 < 16; ++s2) {
      const u64* rp = hp + arow * 64 + 4 * s2 + 2 * q;
      a0[s2] = ald64(rp); a1[s2] = ald64(rp + 1);
    }
    // Gx[s] loads issued early (consumed at cell time)
    const float* slab = p.gx + (size_t)(s % p.R) * 65536u;
    u64 g[2][4];
#pragma unroll
    for (int kk = 0; kk < 2; ++kk) {
      int pp = tid + 256 * kk, b = pp >> 3, u2 = (pp & 7) * 2;
      const float* gb = slab + b * 1024 + sub * 64 + u2;
      g[kk][0] = ald64((const u64*)gb);
      g[kk][1] = ald64((const u64*)(gb + 16));
      g[kk][2] = ald64((const u64*)(gb + 32));
      g[kk][3] = ald64((const u64*)(gb + 48));
    }

    floatx16 acc;
#pragma unroll
    for (int e = 0; e < 16; ++e) acc[e] = 0.f;
#pragma unroll
    for (int s2 = 0; s2 < 16; ++s2)
      acc = __builtin_amdgcn_mfma_f32_32x32x16_bf16(mk_frag(a0[s2], a1[s2]), wf[s2], acc, 0, 0, 0);

    __syncthreads();  // prev-round cst readers done
#pragma unroll
    for (int e = 0; e < 16; ++e) {
      int ri = (e & 3) + 8 * (e >> 2) + 4 * q;
      cst[(mh * 32 + ri) * 68 + nh * 32 + lr] = acc[e];
    }
    __syncthreads();

    uint16_t* hout = p.h1 + (s & (H1R - 1)) * 16384;
#pragma unroll
    for (int kk = 0; kk < 2; ++kk) {
      int pp = tid + 256 * kk, b = pp >> 3, u2 = (pp & 7) * 2;
      float2 pf = *(float2*)&cst[b * 68 +      u2];
      float2 pi = *(float2*)&cst[b * 68 + 16 + u2];
      float2 pg = *(float2*)&cst[b * 68 + 32 + u2];
      float2 po = *(float2*)&cst[b * 68 + 48 + u2];
      float2 gf = u2f2(g[kk][0]), gi = u2f2(g[kk][1]);
      float2 gg = u2f2(g[kk][2]), go = u2f2(g[kk][3]);
      float hv[2];
#pragma unroll
      for (int j = 0; j < 2; ++j) {
        float fj = sigf((j ? pf.y : pf.x) + (j ? gf.y : gf.x) + biasl[u2 + j]);
        float ij = sigf((j ? pi.y : pi.x) + (j ? gi.y : gi.x) + biasl[16 + u2 + j]);
        float gj = tanhf_fast((j ? pg.y : pg.x) + (j ? gg.y : gg.x) + biasl[32 + u2 + j]);
        float oj = sigf((j ? po.y : po.x) + (j ? go.y : go.x) + biasl[48 + u2 + j]);
        float cn = fj * cs[kk][j] + ij * gj;
        cs[kk][j] = cn;
        hv[j] = oj * tanhf_fast(cn);
      }
      ast32((u32*)(hout + b * 256 + sub * 16 + u2), pack2(hv[0], hv[1]));
    }
    __syncthreads();                       // drains all threads' scoped stores
    if (tid == 0) ast32(&p.fl0[sub], (u32)(s + 1));
  }
}

// ---------------- Layer 1: z = [h1[s] | h2[s-1]], K=512 ----------------------
__device__ void run_l1(const KParams& p, int sub, float* cst, float* biasl, char* smem)
{
  const int tid = threadIdx.x;
  const int w = tid >> 6, l = tid & 63, q = l >> 5, lr = l & 31;
  const int mh = w & 1, nh = w >> 1;
  const int arow = mh * 32 + lr;

  if (tid < 64) biasl[tid] = p.b2[tid >> 4][sub * 16 + (tid & 15)];

  const int c = nh * 32 + lr;
  const float* Wg = p.W2[c >> 4];
  const int un = sub * 16 + (c & 15);
  bf16x8 wfA[16], wfB[16];
#pragma unroll
  for (int s = 0; s < 16; ++s)
#pragma unroll
    for (int j = 0; j < 8; ++j) {
      int k = 16 * s + 8 * q + j;
      wfA[s][j] = (bf16_t)Wg[k * 256 + un];
      wfB[s][j] = (bf16_t)Wg[(256 + k) * 256 + un];
    }
  __syncthreads();

  float cs[2][2] = {{0.f, 0.f}, {0.f, 0.f}};

  for (int s = 0; s < 512; ++s) {
    waitcond(p.fl1, (u32)s, p.fl0, (u32)(s + 1), p.fl0, 0u);

    const u64* hp1 = (const u64*)(p.h1 + (s & (H1R - 1)) * 16384);
    const u64* hp2 = (const u64*)(p.h2 + ((s + 1) & 1) * 16384);
    u64 a0[16], a1[16], b0[16], b1[16];
#pragma unroll
    for (int s2 = 0; s2 < 16; ++s2) {
      const u64* rp1 = hp1 + arow * 64 + 4 * s2 + 2 * q;
      const u64* rp2 = hp2 + arow * 64 + 4 * s2 + 2 * q;
      a0[s2] = ald64(rp1); a1[s2] = ald64(rp1 + 1);
      b0[s2] = ald64(rp2); b1[s2] = ald64(rp2 + 1);
    }

    floatx16 acc;
#pragma unroll
    for (int e = 0; e < 16; ++e) acc[e] = 0.f;
#pragma unroll
    for (int s2 = 0; s2 < 16; ++s2)
      acc = __builtin_amdgcn_mfma_f32_32x32x16_bf16(mk_frag(a0[s2], a1[s2]), wfA[s2], acc, 0, 0, 0);
#pragma unroll
    for (int s2 = 0; s2 < 16; ++s2)
      acc = __builtin_amdgcn_mfma_f32_32x32x16_bf16(mk_frag(b0[s2], b1[s2]), wfB[s2], acc, 0, 0, 0);

    __syncthreads();
#pragma unroll
    for (int e = 0; e < 16; ++e) {
      int ri = (e & 3) + 8 * (e >> 2) + 4 * q;
      cst[(mh * 32 + ri) * 68 + nh * 32 + lr] = acc[e];
    }
    __syncthreads();

    uint16_t* hout = p.h2 + (s & 1) * 16384;
#pragma unroll
    for (int kk = 0; kk < 2; ++kk) {
      int pp = tid + 256 * kk, b = pp >> 3, u2 = (pp & 7) * 2;
      float2 pf = *(float2*)&cst[b * 68 +      u2];
      float2 pi = *(float2*)&cst[b * 68 + 16 + u2];
      float2 pg = *(float2*)&cst[b * 68 + 32 + u2];
      float2 po = *(float2*)&cst[b * 68 + 48 + u2];
      float hv[2];
#pragma unroll
      for (int j = 0; j < 2; ++j) {
        float fj = sigf((j ? pf.y : pf.x) + biasl[u2 + j]);
        float ij = sigf((j ? pi.y : pi.x) + biasl[16 + u2 + j]);
        float gj = tanhf_fast((j ? pg.y : pg.x) + biasl[32 + u2 + j]);
        float oj = sigf((j ? po.y : po.x) + biasl[48 + u2 + j]);
        float cn = fj * cs[kk][j] + ij * gj;
        cs[kk][j] = cn;
        hv[j] = oj * tanhf_fast(cn);
      }
      ast32((u32*)(hout + b * 256 + sub * 16 + u2), pack2(hv[0], hv[1]));
    }
    __syncthreads();
    if (tid == 0) ast32(&p.fl1[sub], (u32)(s + 1));
  }

  // ---- dense head part 1: this WG computes 8 cols of d = relu(h2_last@Wd+bd) --
  waitcond(p.fl1, 512u, p.fl0, 0u, p.fl0, 0u);
  {
    const u64* hp = (const u64*)(p.h2 + 16384);   // h2[511] slab 1
    u64 tmp[16];
#pragma unroll
    for (int t = 0; t < 16; ++t) tmp[t] = ald64(hp + tid + 256 * t);
#pragma unroll
    for (int t = 0; t < 16; ++t) {
      int i = tid + 256 * t, b = i >> 6, cc = i & 63;
      *(u64*)(smem + b * 544 + cc * 8) = tmp[t];
    }
  }
  __syncthreads();
  for (int idx = tid; idx < 512; idx += 256) {
    int b = idx >> 3, cc = sub * 8 + (idx & 7);
    const bf16_t* hrow = (const bf16_t*)(smem + b * 544);
    float a = p.bd[cc];
#pragma unroll 8
    for (int k = 0; k < 256; ++k) a += (float)hrow[k] * p.Wd[k * 128 + cc];
    ast32((u32*)&p.dstage[b * 128 + cc], __builtin_bit_cast(u32, fmaxf(a, 0.f)));
  }
  __syncthreads();
  if (tid == 0) ast32(&p.fl1[sub], 513u);

  // ---- final: out = sigmoid(d @ Wout + bout), by L1 WG 0 --------------------
  if (sub == 0) {
    waitcond(p.fl1, 513u, p.fl0, 0u, p.fl0, 0u);
    if (tid < 64) {
      float a = p.bout[0];
#pragma unroll 8
      for (int cc = 0; cc < 128; ++cc) {
        u32 dv = ald32((u32*)&p.dstage[tid * 128 + cc]);
        a += __builtin_bit_cast(float, dv) * p.Wout[cc];
      }
      p.out[tid] = sigf(a);
    }
  }
}

// ---------------- Gx producers: Gx[s] = x_s @ W1x, K=300 (pad 320) -------------
__device__ void run_prod(const KParams& p, int pw, char* smem)
{
  const int tid = threadIdx.x;
  const int w = tid >> 6, l = tid & 63, q = l >> 5, lr = l & 31;
  const int mh = w & 1, chalf = w >> 1;
  const int R = p.R;

  for (int jj = 0; jj < 512 / NPROD; ++jj) {
    const int s = pw + NPROD * jj;
    if (s >= R)   // ring throttle: L0 must have consumed slab s-R
      waitcond(p.fl0, (u32)(s - R + 1), p.fl0, 0u, p.fl0, 0u);
    __syncthreads();
    {
      int b = tid >> 2, qq = tid & 3;
      int tokv = p.tok[b * 512 + s];
      const float4* src = (const float4*)(p.emb + (size_t)tokv * 300);
      char* dst = smem + b * 656;
      for (int j2 = qq; j2 < 75; j2 += 4) {
        float4 v = src[j2];
        *(u32*)(dst + 8 * j2)     = pack2(v.x, v.y);
        *(u32*)(dst + 8 * j2 + 4) = pack2(v.z, v.w);
      }
      for (int i = tid; i < 640; i += 256) {
        int bb = i / 10, cc2 = i % 10;
        *(u32*)(smem + bb * 656 + 600 + cc2 * 4) = 0u;
      }
    }
    __syncthreads();

    bf16x8 afr[20];
    const char* arow = smem + (mh * 32 + lr) * 656 + q * 16;
#pragma unroll
    for (int kt = 0; kt < 20; ++kt) afr[kt] = *(const bf16x8*)(arow + 32 * kt);

    float* slab = p.gx + (size_t)(s % R) * 65536u;
    for (int c2 = 0; c2 < 16; ++c2) {
      int n = (chalf * 16 + c2) * 32 + lr;
      floatx16 acc;
#pragma unroll
      for (int e = 0; e < 16; ++e) acc[e] = 0.f;
#pragma unroll
      for (int kt = 0; kt < 20; ++kt) {
        bf16x8 bf = ((const bf16x8*)p.w1bf)[(kt * 1024 + n) * 2 + q];
        acc = __builtin_amdgcn_mfma_f32_32x32x16_bf16(afr[kt], bf, acc, 0, 0, 0);
      }
#pragma unroll
      for (int e = 0; e < 16; ++e) {
        int ri = (e & 3) + 8 * (e >> 2) + 4 * q;
        ast32((u32*)(slab + (mh * 32 + ri) * 1024 + n), __builtin_bit_cast(u32, acc[e]));
      }
    }
    __syncthreads();                    // drains all threads' Gx stores
    if (tid == 0) ast32(&p.pflags[s], 1u);
  }
}

__global__ __launch_bounds__(256, 1) void lstm_main(KParams p)
{
  __shared__ __align__(16) char smem[64 * 656];   // producers / cstage / head stage
  __shared__ float biasl[64];
  float* cst = (float*)smem;
  const int wg = blockIdx.x;
  if (wg < 16)       run_l0(p, wg, cst, biasl);
  else if (wg < 32)  run_l1(p, wg - 16, cst, biasl, smem);
  else               run_prod(p, wg - 32, smem);
}

// One-time: W1 x-part (rows 0..299, zero-pad to 320) -> bf16 fragment order.
__global__ void prep_w(KParams p) {
  int idx = blockIdx.x * 256 + threadIdx.x;
  if (idx >= 20 * 1024 * 16) return;
  int kk = idx & 15, n = (idx >> 4) & 1023, kt = idx >> 14;
  int k = kt * 16 + kk;
  int g = (n >> 4) & 3, su = n >> 6, u = n & 15;
  float v = (k < 300) ? p.W1[g][k * 256 + su * 16 + u] : 0.f;
  p.w1bf[idx] = (bf16_t)v;
}

// Zero h rings + flags (ws is re-poisoned 0xAA before every launch)
__global__ void init_ws(u32* ws32) {
  int i = blockIdx.x * 256 + threadIdx.x;
  if (i < 82496) ws32[i] = 0u;   // [0, 329984): h1 ring, h2 ring, fl0, fl1, pflags
}

extern "C" void kernel_launch(void* const* d_in, const int* in_sizes, int n_in,
                              void* d_out, int out_size, void* d_ws, size_t ws_size,
                              hipStream_t stream)
{
  KParams p;
  p.tok = (const int*)d_in[0];
  p.emb = (const float*)d_in[1];
  for (int g = 0; g < 4; ++g) {
    p.W1[g] = (const float*)d_in[2 + 2 * g];
    p.b1[g] = (const float*)d_in[3 + 2 * g];
    p.W2[g] = (const float*)d_in[10 + 2 * g];
    p.b2[g] = (const float*)d_in[11 + 2 * g];
  }
  p.Wd   = (const float*)d_in[18];
  p.bd   = (const float*)d_in[19];
  p.Wout = (const float*)d_in[20];
  p.bout = (const float*)d_in[21];
  p.out  = (float*)d_out;

  char* ws = (char*)d_ws;
  p.h1     = (uint16_t*)ws;               // 8 x 32768 B  -> 262144
  p.h2     = (uint16_t*)(ws + 262144);    // 2 x 32768 B  -> 327680
  p.fl0    = (u32*)(ws + 327680);
  p.fl1    = (u32*)(ws + 327808);
  p.pflags = (u32*)(ws + 327936);         // 512 x 4 B    -> 329984
  p.dstage = (float*)(ws + 330112);       // 32768 B      -> 362880
  p.w1bf   = (bf16_t*)(ws + 362880);      // 655360 B     -> 1018240
  p.gx     = (float*)(ws + 1018240);      // ring: R x 262144 B

  long avail = (long)ws_size - 1018240L;
  int R = (int)(avail / 262144L);
  if (R > 64) R = 64;
  if (R < 1)  R = 1;
  p.R = R;

  hipLaunchKernelGGL(init_ws, dim3(323), dim3(256), 0, stream, (u32*)d_ws);
  hipLaunchKernelGGL(prep_w, dim3(1280), dim3(256), 0, stream, p);
  hipLaunchKernelGGL(lstm_main, dim3(32 + NPROD), dim3(256), 0, stream, p);
}

// Round 5
// 2533.569 us; speedup vs baseline: 2.2454x; 2.2454x over previous
//
#include <hip/hip_runtime.h>
#include <stdint.h>

typedef __bf16 bf16_t;
typedef __bf16 bf16x8 __attribute__((ext_vector_type(8)));
typedef float floatx16 __attribute__((ext_vector_type(16)));
typedef unsigned int u32;
typedef unsigned long long u64;

#define NPROD 64   // Gx producer WGs
#define H1R   8    // h1 ring depth
#define SST   592  // stage row stride bytes: 592%128=80 -> conflict-free ds_read_b128

struct KParams {
  const int* tok;
  const float* emb;
  const float* W1[4]; const float* b1[4];
  const float* W2[4]; const float* b2[4];
  const float* Wd; const float* bd; const float* Wout; const float* bout;
  float* out;
  uint16_t* h1;      // ring: H1R x [64][256] bf16
  uint16_t* h2;      // ring: 2   x [64][256] bf16
  u32* fl0; u32* fl1; u32* pflags;
  float* dstage;     // [64][128] fp32
  bf16_t* w1bf;      // [20][1024][16] fragment-ordered x-weights (bf16)
  float* gx;         // ring: R slabs of [64][1024] fp32
  int R;
};

__device__ __forceinline__ float sigf(float x) { return 1.f / (1.f + __expf(-x)); }
__device__ __forceinline__ float tanhf_fast(float x) { return 1.f - 2.f / (__expf(2.f * x) + 1.f); }

__device__ __forceinline__ u32 pack2(float a, float b) {
  uint16_t x = __builtin_bit_cast(uint16_t, (bf16_t)a);
  uint16_t y = __builtin_bit_cast(uint16_t, (bf16_t)b);
  return ((u32)y << 16) | (u32)x;
}
__device__ __forceinline__ float2 u2f2(u64 v) { union { u64 u; float2 f; } x; x.u = v; return x.f; }

// relaxed agent-scope ops: bypass L1/L2, coherent at LLC
__device__ __forceinline__ u32  ald32(const u32* p) { return __hip_atomic_load(p, __ATOMIC_RELAXED, __HIP_MEMORY_SCOPE_AGENT); }
__device__ __forceinline__ void ast32(u32* p, u32 v) { __hip_atomic_store(p, v, __ATOMIC_RELAXED, __HIP_MEMORY_SCOPE_AGENT); }
__device__ __forceinline__ u64  ald64(const u64* p) { return __hip_atomic_load(p, __ATOMIC_RELAXED, __HIP_MEMORY_SCOPE_AGENT); }

// Wave-parallel dataflow wait (call from wave 0 only, then __syncthreads):
// lanes 0-15: fa[lane]>=na; 16-31: fb[lane-16]>=nb; 32+: *pc>=nc. Monotonic.
__device__ __forceinline__ void waitcond(const u32* fa, u32 na, const u32* fb, u32 nb,
                                         const u32* pc, u32 nc) {
  const int lane = threadIdx.x & 63;
  const u32* ap; u32 need;
  if (lane < 16)      { ap = fa + lane;        need = na; }
  else if (lane < 32) { ap = fb + (lane - 16); need = nb; }
  else                { ap = pc;               need = nc; }
  while (!__all(ald32(ap) >= need)) {}
  __atomic_signal_fence(__ATOMIC_ACQUIRE);
}

// Stage one 64x256 bf16 matrix (scoped, from LLC) into LDS rows of stride SST.
// 16 loads outstanding; per-wave writes are 512B contiguous (conflict-free b64).
__device__ __forceinline__ void stage_h(const u64* hp, char* smem) {
  const int tid = threadIdx.x;
  u64 tmp[16];
#pragma unroll
  for (int t = 0; t < 16; ++t) tmp[t] = ald64(hp + tid + 256 * t);
#pragma unroll
  for (int t = 0; t < 16; ++t) {
    int i = tid + 256 * t, b = i >> 6, cc = i & 63;
    *(u64*)(smem + b * SST + cc * 8) = tmp[t];
  }
}

// ---------------- Layer 0: 16 WGs, each owns 16 units (64 gate cols) ----------
__device__ void run_l0(const KParams& p, int sub, char* abuf, float* cst, float* biasl)
{
  const int tid = threadIdx.x;
  const int w = tid >> 6, l = tid & 63, q = l >> 5, lr = l & 31;
  const int mh = w & 1, nh = w >> 1;

  if (tid < 64) biasl[tid] = p.b1[tid >> 4][sub * 16 + (tid & 15)];

  // W1 h-part rows 300..555 -> register B-fragments (reused 512x)
  const int c = nh * 32 + lr;
  const float* Wg = p.W1[c >> 4];
  const int un = sub * 16 + (c & 15);
  bf16x8 wf[16];
#pragma unroll
  for (int s = 0; s < 16; ++s)
#pragma unroll
    for (int j = 0; j < 8; ++j) {
      int k = 16 * s + 8 * q + j;
      wf[s][j] = (bf16_t)Wg[(300 + k) * 256 + un];
    }
  __syncthreads();

  float cs[2][2] = {{0.f, 0.f}, {0.f, 0.f}};

  for (int s = 0; s < 512; ++s) {
    u32 n1 = (s >= 8) ? (u32)(s - 7) : 0u;  // h1-slab reuse guard vs L1 reader
    if (w == 0) waitcond(p.fl0, (u32)s, p.fl1, n1, &p.pflags[s], 1u);
    __syncthreads();

    // Gx[s] loads issued with the stage loads (consumed at cell time)
    const float* slab = p.gx + (size_t)(s % p.R) * 65536u;
    u64 g[2][4];
#pragma unroll
    for (int kk = 0; kk < 2; ++kk) {
      int pp = tid + 256 * kk, b = pp >> 3, u2 = (pp & 7) * 2;
      const float* gb = slab + b * 1024 + sub * 64 + u2;
      g[kk][0] = ald64((const u64*)gb);
      g[kk][1] = ald64((const u64*)(gb + 16));
      g[kk][2] = ald64((const u64*)(gb + 32));
      g[kk][3] = ald64((const u64*)(gb + 48));
    }
    stage_h((const u64*)(p.h1 + ((s + H1R - 1) & (H1R - 1)) * 16384), abuf);
    __syncthreads();

    floatx16 acc;
#pragma unroll
    for (int e = 0; e < 16; ++e) acc[e] = 0.f;
    const char* arow = abuf + (mh * 32 + lr) * SST + q * 16;
#pragma unroll
    for (int s2 = 0; s2 < 16; ++s2) {
      bf16x8 af = *(const bf16x8*)(arow + 32 * s2);
      acc = __builtin_amdgcn_mfma_f32_32x32x16_bf16(af, wf[s2], acc, 0, 0, 0);
    }
#pragma unroll
    for (int e = 0; e < 16; ++e) {
      int ri = (e & 3) + 8 * (e >> 2) + 4 * q;
      cst[(mh * 32 + ri) * 68 + nh * 32 + lr] = acc[e];
    }
    __syncthreads();

    uint16_t* hout = p.h1 + (s & (H1R - 1)) * 16384;
#pragma unroll
    for (int kk = 0; kk < 2; ++kk) {
      int pp = tid + 256 * kk, b = pp >> 3, u2 = (pp & 7) * 2;
      float2 pf = *(float2*)&cst[b * 68 +      u2];
      float2 pi = *(float2*)&cst[b * 68 + 16 + u2];
      float2 pg = *(float2*)&cst[b * 68 + 32 + u2];
      float2 po = *(float2*)&cst[b * 68 + 48 + u2];
      float2 gf = u2f2(g[kk][0]), gi = u2f2(g[kk][1]);
      float2 gg = u2f2(g[kk][2]), go = u2f2(g[kk][3]);
      float hv[2];
#pragma unroll
      for (int j = 0; j < 2; ++j) {
        float fj = sigf((j ? pf.y : pf.x) + (j ? gf.y : gf.x) + biasl[u2 + j]);
        float ij = sigf((j ? pi.y : pi.x) + (j ? gi.y : gi.x) + biasl[16 + u2 + j]);
        float gj = tanhf_fast((j ? pg.y : pg.x) + (j ? gg.y : gg.x) + biasl[32 + u2 + j]);
        float oj = sigf((j ? po.y : po.x) + (j ? go.y : go.x) + biasl[48 + u2 + j]);
        float cn = fj * cs[kk][j] + ij * gj;
        cs[kk][j] = cn;
        hv[j] = oj * tanhf_fast(cn);
      }
      ast32((u32*)(hout + b * 256 + sub * 16 + u2), pack2(hv[0], hv[1]));
    }
    __syncthreads();                       // drains scoped stores (vmcnt0 + barrier)
    if (tid == 0) ast32(&p.fl0[sub], (u32)(s + 1));
  }
}

// ---------------- Layer 1: z = [h1[s] | h2[s-1]], K=512 ----------------------
// Phase order: h2 (peers, available early) first, then wait for L0's h1[s].
__device__ void run_l1(const KParams& p, int sub, char* abuf, float* cst, float* biasl)
{
  const int tid = threadIdx.x;
  const int w = tid >> 6, l = tid & 63, q = l >> 5, lr = l & 31;
  const int mh = w & 1, nh = w >> 1;

  if (tid < 64) biasl[tid] = p.b2[tid >> 4][sub * 16 + (tid & 15)];

  const int c = nh * 32 + lr;
  const float* Wg = p.W2[c >> 4];
  const int un = sub * 16 + (c & 15);
  bf16x8 wfA[16], wfB[16];
#pragma unroll
  for (int s = 0; s < 16; ++s)
#pragma unroll
    for (int j = 0; j < 8; ++j) {
      int k = 16 * s + 8 * q + j;
      wfA[s][j] = (bf16_t)Wg[k * 256 + un];          // h1 part
      wfB[s][j] = (bf16_t)Wg[(256 + k) * 256 + un];  // h2 part
    }
  __syncthreads();

  float cs[2][2] = {{0.f, 0.f}, {0.f, 0.f}};
  const char* arow = abuf + (mh * 32 + lr) * SST + q * 16;

  for (int s = 0; s < 512; ++s) {
    // phase B: h2[s-1] — needs only L1 peers
    if (w == 0) waitcond(p.fl1, (u32)s, p.fl1, (u32)s, p.fl1, 0u);
    __syncthreads();
    stage_h((const u64*)(p.h2 + ((s + 1) & 1) * 16384), abuf);
    __syncthreads();

    floatx16 acc;
#pragma unroll
    for (int e = 0; e < 16; ++e) acc[e] = 0.f;
#pragma unroll
    for (int s2 = 0; s2 < 16; ++s2) {
      bf16x8 af = *(const bf16x8*)(arow + 32 * s2);
      acc = __builtin_amdgcn_mfma_f32_32x32x16_bf16(af, wfB[s2], acc, 0, 0, 0);
    }

    // phase A: h1[s] from L0
    if (w == 0) waitcond(p.fl0, (u32)(s + 1), p.fl0, (u32)(s + 1), p.fl0, 0u);
    __syncthreads();
    stage_h((const u64*)(p.h1 + (s & (H1R - 1)) * 16384), abuf);
    __syncthreads();
#pragma unroll
    for (int s2 = 0; s2 < 16; ++s2) {
      bf16x8 af = *(const bf16x8*)(arow + 32 * s2);
      acc = __builtin_amdgcn_mfma_f32_32x32x16_bf16(af, wfA[s2], acc, 0, 0, 0);
    }
#pragma unroll
    for (int e = 0; e < 16; ++e) {
      int ri = (e & 3) + 8 * (e >> 2) + 4 * q;
      cst[(mh * 32 + ri) * 68 + nh * 32 + lr] = acc[e];
    }
    __syncthreads();

    uint16_t* hout = p.h2 + (s & 1) * 16384;
#pragma unroll
    for (int kk = 0; kk < 2; ++kk) {
      int pp = tid + 256 * kk, b = pp >> 3, u2 = (pp & 7) * 2;
      float2 pf = *(float2*)&cst[b * 68 +      u2];
      float2 pi = *(float2*)&cst[b * 68 + 16 + u2];
      float2 pg = *(float2*)&cst[b * 68 + 32 + u2];
      float2 po = *(float2*)&cst[b * 68 + 48 + u2];
      float hv[2];
#pragma unroll
      for (int j = 0; j < 2; ++j) {
        float fj = sigf((j ? pf.y : pf.x) + biasl[u2 + j]);
        float ij = sigf((j ? pi.y : pi.x) + biasl[16 + u2 + j]);
        float gj = tanhf_fast((j ? pg.y : pg.x) + biasl[32 + u2 + j]);
        float oj = sigf((j ? po.y : po.x) + biasl[48 + u2 + j]);
        float cn = fj * cs[kk][j] + ij * gj;
        cs[kk][j] = cn;
        hv[j] = oj * tanhf_fast(cn);
      }
      ast32((u32*)(hout + b * 256 + sub * 16 + u2), pack2(hv[0], hv[1]));
    }
    __syncthreads();
    if (tid == 0) ast32(&p.fl1[sub], (u32)(s + 1));
  }

  // ---- dense head part 1: 8 cols of d = relu(h2_last @ Wd + bd) -------------
  if (w == 0) waitcond(p.fl1, 512u, p.fl1, 512u, p.fl1, 0u);
  __syncthreads();
  stage_h((const u64*)(p.h2 + 16384), abuf);   // h2[511] slab 1
  __syncthreads();
  for (int idx = tid; idx < 512; idx += 256) {
    int b = idx >> 3, cc = sub * 8 + (idx & 7);
    const bf16_t* hrow = (const bf16_t*)(abuf + b * SST);
    float a = p.bd[cc];
#pragma unroll 8
    for (int k = 0; k < 256; ++k) a += (float)hrow[k] * p.Wd[k * 128 + cc];
    ast32((u32*)&p.dstage[b * 128 + cc], __builtin_bit_cast(u32, fmaxf(a, 0.f)));
  }
  __syncthreads();
  if (tid == 0) ast32(&p.fl1[sub], 513u);

  // ---- final: out = sigmoid(d @ Wout + bout), by L1 WG 0 --------------------
  if (sub == 0) {
    if (w == 0) waitcond(p.fl1, 513u, p.fl1, 513u, p.fl1, 0u);
    __syncthreads();
    if (tid < 64) {
      float a = p.bout[0];
#pragma unroll 8
      for (int cc = 0; cc < 128; ++cc) {
        u32 dv = ald32((u32*)&p.dstage[tid * 128 + cc]);
        a += __builtin_bit_cast(float, dv) * p.Wout[cc];
      }
      p.out[tid] = sigf(a);
    }
  }
}

// ---------------- Gx producers: Gx[s] = x_s @ W1x, K=300 (pad 320) -------------
__device__ void run_prod(const KParams& p, int pw, char* smem)
{
  const int tid = threadIdx.x;
  const int w = tid >> 6, l = tid & 63, q = l >> 5, lr = l & 31;
  const int mh = w & 1, chalf = w >> 1;
  const int R = p.R;

  for (int jj = 0; jj < 512 / NPROD; ++jj) {
    const int s = pw + NPROD * jj;
    if (s >= R) {  // ring throttle: all L0 WGs must have consumed slab s-R
      if (w == 0) waitcond(p.fl0, (u32)(s - R + 1), p.fl0, (u32)(s - R + 1), p.fl0, 0u);
    }
    __syncthreads();
    {
      int b = tid >> 2, qq = tid & 3;
      int tokv = p.tok[b * 512 + s];
      const float4* src = (const float4*)(p.emb + (size_t)tokv * 300);
      char* dst = smem + b * 656;
      for (int j2 = qq; j2 < 75; j2 += 4) {
        float4 v = src[j2];
        *(u32*)(dst + 8 * j2)     = pack2(v.x, v.y);
        *(u32*)(dst + 8 * j2 + 4) = pack2(v.z, v.w);
      }
      for (int i = tid; i < 640; i += 256) {
        int bb = i / 10, cc2 = i % 10;
        *(u32*)(smem + bb * 656 + 600 + cc2 * 4) = 0u;
      }
    }
    __syncthreads();

    bf16x8 afr[20];
    const char* arow = smem + (mh * 32 + lr) * 656 + q * 16;
#pragma unroll
    for (int kt = 0; kt < 20; ++kt) afr[kt] = *(const bf16x8*)(arow + 32 * kt);

    float* slab = p.gx + (size_t)(s % R) * 65536u;
    for (int c2 = 0; c2 < 16; ++c2) {
      int n = (chalf * 16 + c2) * 32 + lr;
      floatx16 acc;
#pragma unroll
      for (int e = 0; e < 16; ++e) acc[e] = 0.f;
#pragma unroll
      for (int kt = 0; kt < 20; ++kt) {
        bf16x8 bf = ((const bf16x8*)p.w1bf)[(kt * 1024 + n) * 2 + q];
        acc = __builtin_amdgcn_mfma_f32_32x32x16_bf16(afr[kt], bf, acc, 0, 0, 0);
      }
#pragma unroll
      for (int e = 0; e < 16; ++e) {
        int ri = (e & 3) + 8 * (e >> 2) + 4 * q;
        ast32((u32*)(slab + (mh * 32 + ri) * 1024 + n), __builtin_bit_cast(u32, acc[e]));
      }
    }
    __syncthreads();                    // drains Gx scoped stores
    if (tid == 0) ast32(&p.pflags[s], 1u);
  }
}

__global__ __launch_bounds__(256, 1) void lstm_main(KParams p)
{
  __shared__ __align__(16) char smem[64 * 656];   // stage buf (SST rows) / producer buf
  __shared__ float cst[64 * 68];
  __shared__ float biasl[64];
  const int wg = blockIdx.x;
  if (wg < 16)       run_l0(p, wg, smem, cst, biasl);
  else if (wg < 32)  run_l1(p, wg - 16, smem, cst, biasl);
  else               run_prod(p, wg - 32, smem);
}

// One-time: W1 x-part (rows 0..299, zero-pad to 320) -> bf16 fragment order.
__global__ void prep_w(KParams p) {
  int idx = blockIdx.x * 256 + threadIdx.x;
  if (idx >= 20 * 1024 * 16) return;
  int kk = idx & 15, n = (idx >> 4) & 1023, kt = idx >> 14;
  int k = kt * 16 + kk;
  int g = (n >> 4) & 3, su = n >> 6, u = n & 15;
  float v = (k < 300) ? p.W1[g][k * 256 + su * 16 + u] : 0.f;
  p.w1bf[idx] = (bf16_t)v;
}

// Zero h rings + flags (ws is re-poisoned 0xAA before every launch)
__global__ void init_ws(u32* ws32) {
  int i = blockIdx.x * 256 + threadIdx.x;
  if (i < 82496) ws32[i] = 0u;   // [0, 329984): h1 ring, h2 ring, fl0, fl1, pflags
}

extern "C" void kernel_launch(void* const* d_in, const int* in_sizes, int n_in,
                              void* d_out, int out_size, void* d_ws, size_t ws_size,
                              hipStream_t stream)
{
  KParams p;
  p.tok = (const int*)d_in[0];
  p.emb = (const float*)d_in[1];
  for (int g = 0; g < 4; ++g) {
    p.W1[g] = (const float*)d_in[2 + 2 * g];
    p.b1[g] = (const float*)d_in[3 + 2 * g];
    p.W2[g] = (const float*)d_in[10 + 2 * g];
    p.b2[g] = (const float*)d_in[11 + 2 * g];
  }
  p.Wd   = (const float*)d_in[18];
  p.bd   = (const float*)d_in[19];
  p.Wout = (const float*)d_in[20];
  p.bout = (const float*)d_in[21];
  p.out  = (float*)d_out;

  char* ws = (char*)d_ws;
  p.h1     = (uint16_t*)ws;               // 8 x 32768 B  -> 262144
  p.h2     = (uint16_t*)(ws + 262144);    // 2 x 32768 B  -> 327680
  p.fl0    = (u32*)(ws + 327680);
  p.fl1    = (u32*)(ws + 327808);
  p.pflags = (u32*)(ws + 327936);         // 512 x 4 B    -> 329984
  p.dstage = (float*)(ws + 330112);       // 32768 B      -> 362880
  p.w1bf   = (bf16_t*)(ws + 362880);      // 655360 B     -> 1018240
  p.gx     = (float*)(ws + 1018240);      // ring: R x 262144 B

  long avail = (long)ws_size - 1018240L;
  int R = (int)(avail / 262144L);
  if (R > 64) R = 64;
  if (R < 1)  R = 1;
  p.R = R;

  hipLaunchKernelGGL(init_ws, dim3(323), dim3(256), 0, stream, (u32*)d_ws);
  hipLaunchKernelGGL(prep_w, dim3(1280), dim3(256), 0, stream, p);
  hipLaunchKernelGGL(lstm_main, dim3(32 + NPROD), dim3(256), 0, stream, p);
}

// Round 6
// 2332.073 us; speedup vs baseline: 2.4394x; 1.0864x over previous
//
#include <hip/hip_runtime.h>
#include <stdint.h>

typedef __bf16 bf16_t;
typedef __bf16 bf16x8 __attribute__((ext_vector_type(8)));
typedef float floatx16 __attribute__((ext_vector_type(16)));
typedef unsigned int u32;
typedef unsigned long long u64;

#define NPROD 64   // Gx producer WGs
#define H1R   8    // h1 ring depth
#define SST   592  // L0 stage row stride (592%128=80 -> measured conflict-free b128)
#define ZST   1104 // L1 z-tile row stride (1104%256=80 -> same residue class)

struct KParams {
  const int* tok;
  const float* emb;
  const float* W1[4]; const float* b1[4];
  const float* W2[4]; const float* b2[4];
  const float* Wd; const float* bd; const float* Wout; const float* bout;
  float* out;
  uint16_t* h1;      // ring: H1R x [64][256] bf16
  uint16_t* h2;      // ring: 2   x [64][256] bf16
  u32* fl0;          // 16 entries (L0 WGs)
  u32* fl1;          // 32 entries (L1 WGs)
  u32* pflags;       // 512 producer flags
  float* dstage;     // [64][128] fp32
  bf16_t* w1bf;      // [20][1024][16] fragment-ordered x-weights (bf16)
  float* gx;         // ring: R slabs of [64][1024] fp32
  int R;
};

__device__ __forceinline__ float sigf(float x) { return 1.f / (1.f + __expf(-x)); }
__device__ __forceinline__ float tanhf_fast(float x) { return 1.f - 2.f / (__expf(2.f * x) + 1.f); }

__device__ __forceinline__ u32 pack2(float a, float b) {
  uint16_t x = __builtin_bit_cast(uint16_t, (bf16_t)a);
  uint16_t y = __builtin_bit_cast(uint16_t, (bf16_t)b);
  return ((u32)y << 16) | (u32)x;
}
__device__ __forceinline__ float2 u2f2(u64 v) { union { u64 u; float2 f; } x; x.u = v; return x.f; }

// relaxed agent-scope ops: bypass L1/L2, coherent at LLC
__device__ __forceinline__ u32  ald32(const u32* p) { return __hip_atomic_load(p, __ATOMIC_RELAXED, __HIP_MEMORY_SCOPE_AGENT); }
__device__ __forceinline__ void ast32(u32* p, u32 v) { __hip_atomic_store(p, v, __ATOMIC_RELAXED, __HIP_MEMORY_SCOPE_AGENT); }
__device__ __forceinline__ u64  ald64(const u64* p) { return __hip_atomic_load(p, __ATOMIC_RELAXED, __HIP_MEMORY_SCOPE_AGENT); }

// Wave-parallel dataflow wait (wave 0 only, then __syncthreads):
// lanes [0,NA): fa[lane]>=na; [NA,NA+NB): fb[lane-NA]>=nb; rest: *pc>=nc.
template<int NA, int NB>
__device__ __forceinline__ void waitcond(const u32* fa, u32 na, const u32* fb, u32 nb,
                                         const u32* pc, u32 nc) {
  const int lane = threadIdx.x & 63;
  const u32* ap; u32 need;
  if (lane < NA)           { ap = fa + lane;        need = na; }
  else if (lane < NA + NB) { ap = fb + (lane - NA); need = nb; }
  else                     { ap = pc;               need = nc; }
  while (!__all(ald32(ap) >= need)) {}
  __atomic_signal_fence(__ATOMIC_ACQUIRE);
}

// Stage one 64x256 bf16 matrix (scoped, from LLC) into LDS rows of stride SST.
__device__ __forceinline__ void stage_h64(const u64* hp, char* smem) {
  const int tid = threadIdx.x;
  u64 tmp[16];
#pragma unroll
  for (int t = 0; t < 16; ++t) tmp[t] = ald64(hp + tid + 256 * t);
#pragma unroll
  for (int t = 0; t < 16; ++t) {
    int i = tid + 256 * t, b = i >> 6, cc = i & 63;
    *(u64*)(smem + b * SST + cc * 8) = tmp[t];
  }
}

// ---------------- Layer 0: 16 WGs, each owns 16 units (64 gate cols) ----------
__device__ void run_l0(const KParams& p, int sub, char* abuf, float* cst, float* biasl)
{
  const int tid = threadIdx.x;
  const int w = tid >> 6, l = tid & 63, q = l >> 5, lr = l & 31;
  const int mh = w & 1, nh = w >> 1;

  if (tid < 64) biasl[tid] = p.b1[tid >> 4][sub * 16 + (tid & 15)];

  // W1 h-part rows 300..555 -> register B-fragments (reused 512x)
  const int c = nh * 32 + lr;
  const float* Wg = p.W1[c >> 4];
  const int un = sub * 16 + (c & 15);
  bf16x8 wf[16];
#pragma unroll
  for (int s = 0; s < 16; ++s)
#pragma unroll
    for (int j = 0; j < 8; ++j) {
      int k = 16 * s + 8 * q + j;
      wf[s][j] = (bf16_t)Wg[(300 + k) * 256 + un];
    }
  __syncthreads();

  float cs[2][2] = {{0.f, 0.f}, {0.f, 0.f}};

  for (int s = 0; s < 512; ++s) {
    u32 n1 = (s >= 8) ? (u32)(s - 7) : 0u;  // h1-slab reuse guard vs 32 L1 readers
    if (w == 0) waitcond<16, 32>(p.fl0, (u32)s, p.fl1, n1, &p.pflags[s], 1u);
    __syncthreads();

    // Gx[s] loads issued with the stage loads (consumed at cell time)
    const float* slab = p.gx + (size_t)(s % p.R) * 65536u;
    u64 g[2][4];
#pragma unroll
    for (int kk = 0; kk < 2; ++kk) {
      int pp = tid + 256 * kk, b = pp >> 3, u2 = (pp & 7) * 2;
      const float* gb = slab + b * 1024 + sub * 64 + u2;
      g[kk][0] = ald64((const u64*)gb);
      g[kk][1] = ald64((const u64*)(gb + 16));
      g[kk][2] = ald64((const u64*)(gb + 32));
      g[kk][3] = ald64((const u64*)(gb + 48));
    }
    stage_h64((const u64*)(p.h1 + ((s + H1R - 1) & (H1R - 1)) * 16384), abuf);
    __syncthreads();

    floatx16 acc;
#pragma unroll
    for (int e = 0; e < 16; ++e) acc[e] = 0.f;
    const char* arow = abuf + (mh * 32 + lr) * SST + q * 16;
#pragma unroll
    for (int s2 = 0; s2 < 16; ++s2) {
      bf16x8 af = *(const bf16x8*)(arow + 32 * s2);
      acc = __builtin_amdgcn_mfma_f32_32x32x16_bf16(af, wf[s2], acc, 0, 0, 0);
    }
#pragma unroll
    for (int e = 0; e < 16; ++e) {
      int ri = (e & 3) + 8 * (e >> 2) + 4 * q;
      cst[(mh * 32 + ri) * 68 + nh * 32 + lr] = acc[e];
    }
    __syncthreads();

    uint16_t* hout = p.h1 + (s & (H1R - 1)) * 16384;
#pragma unroll
    for (int kk = 0; kk < 2; ++kk) {
      int pp = tid + 256 * kk, b = pp >> 3, u2 = (pp & 7) * 2;
      float2 pf = *(float2*)&cst[b * 68 +      u2];
      float2 pi = *(float2*)&cst[b * 68 + 16 + u2];
      float2 pg = *(float2*)&cst[b * 68 + 32 + u2];
      float2 po = *(float2*)&cst[b * 68 + 48 + u2];
      float2 gf = u2f2(g[kk][0]), gi = u2f2(g[kk][1]);
      float2 gg = u2f2(g[kk][2]), go = u2f2(g[kk][3]);
      float hv[2];
#pragma unroll
      for (int j = 0; j < 2; ++j) {
        float fj = sigf((j ? pf.y : pf.x) + (j ? gf.y : gf.x) + biasl[u2 + j]);
        float ij = sigf((j ? pi.y : pi.x) + (j ? gi.y : gi.x) + biasl[16 + u2 + j]);
        float gj = tanhf_fast((j ? pg.y : pg.x) + (j ? gg.y : gg.x) + biasl[32 + u2 + j]);
        float oj = sigf((j ? po.y : po.x) + (j ? go.y : go.x) + biasl[48 + u2 + j]);
        float cn = fj * cs[kk][j] + ij * gj;
        cs[kk][j] = cn;
        hv[j] = oj * tanhf_fast(cn);
      }
      ast32((u32*)(hout + b * 256 + sub * 16 + u2), pack2(hv[0], hv[1]));
    }
    __syncthreads();                       // drains scoped stores (vmcnt0 + barrier)
    if (tid == 0) ast32(&p.fl0[sub], (u32)(s + 1));
  }
}

// ---------------- Layer 1: 32 WGs, each 32 batch rows x 16 units, K=512 -------
// One merged wait + one stage (h1[s] | h2[s-1] into one 32x512 z-tile) per step.
// 4 waves = (col-tile nh) x (K-half kh); partial sums via 2-plane cst.
__device__ void run_l1(const KParams& p, int w2, char* zbuf, float* cst, float* biasl)
{
  const int tid = threadIdx.x;
  const int wv = tid >> 6, l = tid & 63, q = l >> 5, lr = l & 31;
  const int nh = wv & 1, kh = wv >> 1;
  const int bh = w2 & 1, sub1 = w2 >> 1;

  if (tid < 64) biasl[tid] = p.b2[tid >> 4][sub1 * 16 + (tid & 15)];

  const int c = nh * 32 + lr;
  const float* Wg = p.W2[c >> 4];
  const int un = sub1 * 16 + (c & 15);
  bf16x8 wf[16];   // this wave's K-half of W2 (z rows kh*256..+256)
#pragma unroll
  for (int s = 0; s < 16; ++s)
#pragma unroll
    for (int j = 0; j < 8; ++j) {
      int k = kh * 256 + s * 16 + q * 8 + j;
      wf[s][j] = (bf16_t)Wg[k * 256 + un];
    }
  __syncthreads();

  float cs2[2] = {0.f, 0.f};   // c-state: thread owns (b = tid>>3, units u2,u2+1)
  const int cb = tid >> 3, cu = (tid & 7) * 2;

  for (int s = 0; s < 512; ++s) {
    // merged wait: all 32 L1 peers done s-1 (h2 ready) AND all 16 L0 done s (h1 ready)
    if (wv == 0) waitcond<32, 16>(p.fl1, (u32)s, p.fl0, (u32)(s + 1), p.fl0, 0u);
    __syncthreads();

    // stage z = [h1[s] | h2[s-1]] rows bh*32..+32, all 16 loads in flight
    const u64* hp1 = (const u64*)(p.h1 + (s & (H1R - 1)) * 16384) + bh * 2048;
    const u64* hp2 = (const u64*)(p.h2 + ((s + 1) & 1) * 16384) + bh * 2048;
    u64 t1[8], t2[8];
#pragma unroll
    for (int t = 0; t < 8; ++t) t1[t] = ald64(hp1 + tid + 256 * t);
#pragma unroll
    for (int t = 0; t < 8; ++t) t2[t] = ald64(hp2 + tid + 256 * t);
#pragma unroll
    for (int t = 0; t < 8; ++t) {
      int i = tid + 256 * t, r = i >> 6, cc = i & 63;
      *(u64*)(zbuf + r * ZST + cc * 8) = t1[t];
    }
#pragma unroll
    for (int t = 0; t < 8; ++t) {
      int i = tid + 256 * t, r = i >> 6, cc = i & 63;
      *(u64*)(zbuf + r * ZST + 512 + cc * 8) = t2[t];
    }
    __syncthreads();

    floatx16 acc;
#pragma unroll
    for (int e = 0; e < 16; ++e) acc[e] = 0.f;
    const char* arow = zbuf + lr * ZST + kh * 512 + q * 16;
#pragma unroll
    for (int s2 = 0; s2 < 16; ++s2) {
      bf16x8 af = *(const bf16x8*)(arow + 32 * s2);
      acc = __builtin_amdgcn_mfma_f32_32x32x16_bf16(af, wf[s2], acc, 0, 0, 0);
    }
#pragma unroll
    for (int e = 0; e < 16; ++e) {
      int ri = (e & 3) + 8 * (e >> 2) + 4 * q;
      cst[kh * 2176 + ri * 68 + nh * 32 + lr] = acc[e];
    }
    __syncthreads();

    // cell: sum the two K-half planes + bias
    uint16_t* hout = p.h2 + (s & 1) * 16384;
    {
      float2 pf = *(float2*)&cst[cb * 68 +      cu];
      float2 pi = *(float2*)&cst[cb * 68 + 16 + cu];
      float2 pg = *(float2*)&cst[cb * 68 + 32 + cu];
      float2 po = *(float2*)&cst[cb * 68 + 48 + cu];
      float2 qf = *(float2*)&cst[2176 + cb * 68 +      cu];
      float2 qi = *(float2*)&cst[2176 + cb * 68 + 16 + cu];
      float2 qg = *(float2*)&cst[2176 + cb * 68 + 32 + cu];
      float2 qo = *(float2*)&cst[2176 + cb * 68 + 48 + cu];
      float hv[2];
#pragma unroll
      for (int j = 0; j < 2; ++j) {
        float fj = sigf((j ? pf.y + qf.y : pf.x + qf.x) + biasl[cu + j]);
        float ij = sigf((j ? pi.y + qi.y : pi.x + qi.x) + biasl[16 + cu + j]);
        float gj = tanhf_fast((j ? pg.y + qg.y : pg.x + qg.x) + biasl[32 + cu + j]);
        float oj = sigf((j ? po.y + qo.y : po.x + qo.x) + biasl[48 + cu + j]);
        float cn = fj * cs2[j] + ij * gj;
        cs2[j] = cn;
        hv[j] = oj * tanhf_fast(cn);
      }
      ast32((u32*)(hout + (bh * 32 + cb) * 256 + sub1 * 16 + cu), pack2(hv[0], hv[1]));
    }
    __syncthreads();
    if (tid == 0) ast32(&p.fl1[w2], (u32)(s + 1));
  }

  // ---- dense head part 1: 4 cols of d = relu(h2_last @ Wd + bd) -------------
  if (wv == 0) waitcond<32, 16>(p.fl1, 512u, p.fl0, 0u, p.fl0, 0u);
  __syncthreads();
  {
    const u64* hp = (const u64*)(p.h2 + 16384);   // h2[511] slab 1
    u64 tmp[16];
#pragma unroll
    for (int t = 0; t < 16; ++t) tmp[t] = ald64(hp + tid + 256 * t);
#pragma unroll
    for (int t = 0; t < 16; ++t) {
      int i = tid + 256 * t, b = i >> 6, cc = i & 63;
      *(u64*)(zbuf + b * 520 + cc * 8) = tmp[t];
    }
  }
  __syncthreads();
  {
    int b = tid >> 2, cc = w2 * 4 + (tid & 3);
    const bf16_t* hrow = (const bf16_t*)(zbuf + b * 520);
    float a = p.bd[cc];
#pragma unroll 8
    for (int k = 0; k < 256; ++k) a += (float)hrow[k] * p.Wd[k * 128 + cc];
    ast32((u32*)&p.dstage[b * 128 + cc], __builtin_bit_cast(u32, fmaxf(a, 0.f)));
  }
  __syncthreads();
  if (tid == 0) ast32(&p.fl1[w2], 513u);

  // ---- final: out = sigmoid(d @ Wout + bout), by L1 WG 0 --------------------
  if (w2 == 0) {
    if (wv == 0) waitcond<32, 16>(p.fl1, 513u, p.fl0, 0u, p.fl0, 0u);
    __syncthreads();
    if (tid < 64) {
      float a = p.bout[0];
#pragma unroll 8
      for (int cc = 0; cc < 128; ++cc) {
        u32 dv = ald32((u32*)&p.dstage[tid * 128 + cc]);
        a += __builtin_bit_cast(float, dv) * p.Wout[cc];
      }
      p.out[tid] = sigf(a);
    }
  }
}

// ---------------- Gx producers: Gx[s] = x_s @ W1x, K=300 (pad 320) -------------
__device__ void run_prod(const KParams& p, int pw, char* smem)
{
  const int tid = threadIdx.x;
  const int w = tid >> 6, l = tid & 63, q = l >> 5, lr = l & 31;
  const int mh = w & 1, chalf = w >> 1;
  const int R = p.R;

  for (int jj = 0; jj < 512 / NPROD; ++jj) {
    const int s = pw + NPROD * jj;
    if (s >= R) {  // ring throttle: all L0 WGs must have consumed slab s-R
      if (w == 0) waitcond<16, 16>(p.fl0, (u32)(s - R + 1), p.fl0, (u32)(s - R + 1), p.fl0, 0u);
    }
    __syncthreads();
    {
      int b = tid >> 2, qq = tid & 3;
      int tokv = p.tok[b * 512 + s];
      const float4* src = (const float4*)(p.emb + (size_t)tokv * 300);
      char* dst = smem + b * 656;
      for (int j2 = qq; j2 < 75; j2 += 4) {
        float4 v = src[j2];
        *(u32*)(dst + 8 * j2)     = pack2(v.x, v.y);
        *(u32*)(dst + 8 * j2 + 4) = pack2(v.z, v.w);
      }
      for (int i = tid; i < 640; i += 256) {
        int bb = i / 10, cc2 = i % 10;
        *(u32*)(smem + bb * 656 + 600 + cc2 * 4) = 0u;
      }
    }
    __syncthreads();

    bf16x8 afr[20];
    const char* arow = smem + (mh * 32 + lr) * 656 + q * 16;
#pragma unroll
    for (int kt = 0; kt < 20; ++kt) afr[kt] = *(const bf16x8*)(arow + 32 * kt);

    float* slab = p.gx + (size_t)(s % R) * 65536u;
    for (int c2 = 0; c2 < 16; ++c2) {
      int n = (chalf * 16 + c2) * 32 + lr;
      floatx16 acc;
#pragma unroll
      for (int e = 0; e < 16; ++e) acc[e] = 0.f;
#pragma unroll
      for (int kt = 0; kt < 20; ++kt) {
        bf16x8 bf = ((const bf16x8*)p.w1bf)[(kt * 1024 + n) * 2 + q];
        acc = __builtin_amdgcn_mfma_f32_32x32x16_bf16(afr[kt], bf, acc, 0, 0, 0);
      }
#pragma unroll
      for (int e = 0; e < 16; ++e) {
        int ri = (e & 3) + 8 * (e >> 2) + 4 * q;
        ast32((u32*)(slab + (mh * 32 + ri) * 1024 + n), __builtin_bit_cast(u32, acc[e]));
      }
    }
    __syncthreads();                    // drains Gx scoped stores
    if (tid == 0) ast32(&p.pflags[s], 1u);
  }
}

__global__ __launch_bounds__(256, 1) void lstm_main(KParams p)
{
  __shared__ __align__(16) char smem[64 * 656];   // L0 stage / L1 z-tile / producer buf
  __shared__ float cst[4352];                     // L0: [64][68]; L1: [2][32][68]
  __shared__ float biasl[64];
  const int wg = blockIdx.x;
  if (wg < 16)       run_l0(p, wg, smem, cst, biasl);
  else if (wg < 48)  run_l1(p, wg - 16, smem, cst, biasl);
  else               run_prod(p, wg - 48, smem);
}

// One-time: W1 x-part (rows 0..299, zero-pad to 320) -> bf16 fragment order.
__global__ void prep_w(KParams p) {
  int idx = blockIdx.x * 256 + threadIdx.x;
  if (idx >= 20 * 1024 * 16) return;
  int kk = idx & 15, n = (idx >> 4) & 1023, kt = idx >> 14;
  int k = kt * 16 + kk;
  int g = (n >> 4) & 3, su = n >> 6, u = n & 15;
  float v = (k < 300) ? p.W1[g][k * 256 + su * 16 + u] : 0.f;
  p.w1bf[idx] = (bf16_t)v;
}

// Zero h rings + flags (ws is re-poisoned 0xAA before every launch)
__global__ void init_ws(u32* ws32) {
  int i = blockIdx.x * 256 + threadIdx.x;
  if (i < 82496) ws32[i] = 0u;   // [0, 329984): h1 ring, h2 ring, fl0, fl1, pflags
}

extern "C" void kernel_launch(void* const* d_in, const int* in_sizes, int n_in,
                              void* d_out, int out_size, void* d_ws, size_t ws_size,
                              hipStream_t stream)
{
  KParams p;
  p.tok = (const int*)d_in[0];
  p.emb = (const float*)d_in[1];
  for (int g = 0; g < 4; ++g) {
    p.W1[g] = (const float*)d_in[2 + 2 * g];
    p.b1[g] = (const float*)d_in[3 + 2 * g];
    p.W2[g] = (const float*)d_in[10 + 2 * g];
    p.b2[g] = (const float*)d_in[11 + 2 * g];
  }
  p.Wd   = (const float*)d_in[18];
  p.bd   = (const float*)d_in[19];
  p.Wout = (const float*)d_in[20];
  p.bout = (const float*)d_in[21];
  p.out  = (float*)d_out;

  char* ws = (char*)d_ws;
  p.h1     = (uint16_t*)ws;               // 8 x 32768 B  -> 262144
  p.h2     = (uint16_t*)(ws + 262144);    // 2 x 32768 B  -> 327680
  p.fl0    = (u32*)(ws + 327680);         // 16 x 4 B
  p.fl1    = (u32*)(ws + 327808);         // 32 x 4 B
  p.pflags = (u32*)(ws + 327936);         // 512 x 4 B    -> 329984
  p.dstage = (float*)(ws + 330112);       // 32768 B      -> 362880
  p.w1bf   = (bf16_t*)(ws + 362880);      // 655360 B     -> 1018240
  p.gx     = (float*)(ws + 1018240);      // ring: R x 262144 B

  long avail = (long)ws_size - 1018240L;
  int R = (int)(avail / 262144L);
  if (R > 64) R = 64;
  if (R < 1)  R = 1;
  p.R = R;

  hipLaunchKernelGGL(init_ws, dim3(323), dim3(256), 0, stream, (u32*)d_ws);
  hipLaunchKernelGGL(prep_w, dim3(1280), dim3(256), 0, stream, p);
  hipLaunchKernelGGL(lstm_main, dim3(16 + 32 + NPROD), dim3(256), 0, stream, p);
}

// Round 8
// 1842.248 us; speedup vs baseline: 3.0880x; 1.2659x over previous
//
#include <hip/hip_runtime.h>
#include <stdint.h>

typedef __bf16 bf16_t;
typedef __bf16 bf16x8 __attribute__((ext_vector_type(8)));
typedef float floatx16 __attribute__((ext_vector_type(16)));
typedef unsigned int u32;
typedef unsigned long long u64;

#define NPROD 64   // Gx producer WGs
#define H1R   8    // h1 ring depth
#define SST   592  // L0 stage row stride (592%128=80 -> measured conflict-free b128)
#define ZST   1104 // L1 z-tile row stride (1104%256=80 -> same residue class)
#define FP    32   // flag padding: 32 u32 = 128 B per flag (one LLC line each)

struct KParams {
  const int* tok;
  const float* emb;
  const float* W1[4]; const float* b1[4];
  const float* W2[4]; const float* b2[4];
  const float* Wd; const float* bd; const float* Wout; const float* bout;
  float* out;
  uint16_t* h1;      // ring: H1R x [64][256] bf16
  uint16_t* h2;      // ring: 2   x [64][256] bf16
  u32* fl0;          // 16 flags, 128B-padded (polled by L0/L1 only)
  u32* fl1;          // 32 flags, 128B-padded
  u32* fl0g;         // 16 flags, 128B-padded (producer-only mirror of fl0)
  u32* pflags;       // 512 flags, 128B-padded (producers -> L0)
  float* dstage;     // [64][128] fp32
  bf16_t* w1bf;      // [20][1024][16] fragment-ordered x-weights (bf16)
  float* gx;         // ring: R slabs of [64][1024] fp32
  int R;
};

__device__ __forceinline__ float sigf(float x) { return 1.f / (1.f + __expf(-x)); }
__device__ __forceinline__ float tanhf_fast(float x) { return 1.f - 2.f / (__expf(2.f * x) + 1.f); }

__device__ __forceinline__ u32 pack2(float a, float b) {
  uint16_t x = __builtin_bit_cast(uint16_t, (bf16_t)a);
  uint16_t y = __builtin_bit_cast(uint16_t, (bf16_t)b);
  return ((u32)y << 16) | (u32)x;
}
__device__ __forceinline__ float2 u2f2(u64 v) { union { u64 u; float2 f; } x; x.u = v; return x.f; }

// relaxed agent-scope ops: bypass L1/L2, coherent at LLC
__device__ __forceinline__ u32  ald32(const u32* p) { return __hip_atomic_load(p, __ATOMIC_RELAXED, __HIP_MEMORY_SCOPE_AGENT); }
__device__ __forceinline__ void ast32(u32* p, u32 v) { __hip_atomic_store(p, v, __ATOMIC_RELAXED, __HIP_MEMORY_SCOPE_AGENT); }
__device__ __forceinline__ u64  ald64(const u64* p) { return __hip_atomic_load(p, __ATOMIC_RELAXED, __HIP_MEMORY_SCOPE_AGENT); }

// Wave-parallel dataflow wait (wave 0 only, then __syncthreads):
// lanes [0,NA): fa[lane*FP]>=na; [NA,NA+NB): fb[(lane-NA)*FP]>=nb; rest: *pc>=nc.
template<int NA, int NB>
__device__ __forceinline__ void waitcond(const u32* fa, u32 na, const u32* fb, u32 nb,
                                         const u32* pc, u32 nc) {
  const int lane = threadIdx.x & 63;
  const u32* ap; u32 need;
  if (lane < NA)           { ap = fa + lane * FP;        need = na; }
  else if (lane < NA + NB) { ap = fb + (lane - NA) * FP; need = nb; }
  else                     { ap = pc;                    need = nc; }
  while (!__all(ald32(ap) >= need)) {}
  __atomic_signal_fence(__ATOMIC_ACQUIRE);
}

// producer-side wait on the 16-flag mirror (keeps poll traffic off fl0's lines)
__device__ __forceinline__ void waitg16(const u32* fa, u32 na) {
  const int lane = threadIdx.x & 63;
  const u32* ap = fa + (lane & 15) * FP;
  while (!__all(ald32(ap) >= na)) {}
  __atomic_signal_fence(__ATOMIC_ACQUIRE);
}

// Stage one 64x256 bf16 matrix (scoped, from LLC) into LDS rows of stride SST.
__device__ __forceinline__ void stage_h64(const u64* hp, char* smem) {
  const int tid = threadIdx.x;
  u64 tmp[16];
#pragma unroll
  for (int t = 0; t < 16; ++t) tmp[t] = ald64(hp + tid + 256 * t);
#pragma unroll
  for (int t = 0; t < 16; ++t) {
    int i = tid + 256 * t, b = i >> 6, cc = i & 63;
    *(u64*)(smem + b * SST + cc * 8) = tmp[t];
  }
}

// ---------------- Layer 0: 16 WGs, each owns 16 units (64 gate cols) ----------
__device__ void run_l0(const KParams& p, int sub, char* abuf, float* cst, float* biasl)
{
  const int tid = threadIdx.x;
  const int w = tid >> 6, l = tid & 63, q = l >> 5, lr = l & 31;
  const int mh = w & 1, nh = w >> 1;

  if (tid < 64) biasl[tid] = p.b1[tid >> 4][sub * 16 + (tid & 15)];

  // W1 h-part rows 300..555 -> register B-fragments (reused 512x)
  const int c = nh * 32 + lr;
  const float* Wg = p.W1[c >> 4];
  const int un = sub * 16 + (c & 15);
  bf16x8 wf[16];
#pragma unroll
  for (int s = 0; s < 16; ++s)
#pragma unroll
    for (int j = 0; j < 8; ++j) {
      int k = 16 * s + 8 * q + j;
      wf[s][j] = (bf16_t)Wg[(300 + k) * 256 + un];
    }
  __syncthreads();

  float cs[2][2] = {{0.f, 0.f}, {0.f, 0.f}};

  for (int s = 0; s < 512; ++s) {
    u32 n1 = (s >= 8) ? (u32)(s - 7) : 0u;  // h1-slab reuse guard vs 32 L1 readers
    if (w == 0) waitcond<16, 32>(p.fl0, (u32)s, p.fl1, n1, &p.pflags[s * FP], 1u);
    __syncthreads();

    // Gx[s] loads issued with the stage loads (consumed at cell time)
    const float* slab = p.gx + (size_t)(s % p.R) * 65536u;
    u64 g[2][4];
#pragma unroll
    for (int kk = 0; kk < 2; ++kk) {
      int pp = tid + 256 * kk, b = pp >> 3, u2 = (pp & 7) * 2;
      const float* gb = slab + b * 1024 + sub * 64 + u2;
      g[kk][0] = ald64((const u64*)gb);
      g[kk][1] = ald64((const u64*)(gb + 16));
      g[kk][2] = ald64((const u64*)(gb + 32));
      g[kk][3] = ald64((const u64*)(gb + 48));
    }
    stage_h64((const u64*)(p.h1 + ((s + H1R - 1) & (H1R - 1)) * 16384), abuf);
    __syncthreads();

    floatx16 acc;
#pragma unroll
    for (int e = 0; e < 16; ++e) acc[e] = 0.f;
    const char* arow = abuf + (mh * 32 + lr) * SST + q * 16;
#pragma unroll
    for (int s2 = 0; s2 < 16; ++s2) {
      bf16x8 af = *(const bf16x8*)(arow + 32 * s2);
      acc = __builtin_amdgcn_mfma_f32_32x32x16_bf16(af, wf[s2], acc, 0, 0, 0);
    }
#pragma unroll
    for (int e = 0; e < 16; ++e) {
      int ri = (e & 3) + 8 * (e >> 2) + 4 * q;
      cst[(mh * 32 + ri) * 68 + nh * 32 + lr] = acc[e];
    }
    __syncthreads();

    uint16_t* hout = p.h1 + (s & (H1R - 1)) * 16384;
#pragma unroll
    for (int kk = 0; kk < 2; ++kk) {
      int pp = tid + 256 * kk, b = pp >> 3, u2 = (pp & 7) * 2;
      float2 pf = *(float2*)&cst[b * 68 +      u2];
      float2 pi = *(float2*)&cst[b * 68 + 16 + u2];
      float2 pg = *(float2*)&cst[b * 68 + 32 + u2];
      float2 po = *(float2*)&cst[b * 68 + 48 + u2];
      float2 gf = u2f2(g[kk][0]), gi = u2f2(g[kk][1]);
      float2 gg = u2f2(g[kk][2]), go = u2f2(g[kk][3]);
      float hv[2];
#pragma unroll
      for (int j = 0; j < 2; ++j) {
        float fj = sigf((j ? pf.y : pf.x) + (j ? gf.y : gf.x) + biasl[u2 + j]);
        float ij = sigf((j ? pi.y : pi.x) + (j ? gi.y : gi.x) + biasl[16 + u2 + j]);
        float gj = tanhf_fast((j ? pg.y : pg.x) + (j ? gg.y : gg.x) + biasl[32 + u2 + j]);
        float oj = sigf((j ? po.y : po.x) + (j ? go.y : go.x) + biasl[48 + u2 + j]);
        float cn = fj * cs[kk][j] + ij * gj;
        cs[kk][j] = cn;
        hv[j] = oj * tanhf_fast(cn);
      }
      ast32((u32*)(hout + b * 256 + sub * 16 + u2), pack2(hv[0], hv[1]));
    }
    __syncthreads();                       // drains scoped stores (vmcnt0 + barrier)
    if (tid == 0) {
      ast32(&p.fl0[sub * FP], (u32)(s + 1));    // consumer-polled flag
      ast32(&p.fl0g[sub * FP], (u32)(s + 1));   // producer-polled mirror
    }
  }
}

// ---------------- Layer 1: 32 WGs, each 32 batch rows x 16 units, K=512 -------
// One merged wait + one stage (h1[s] | h2[s-1] into one 32x512 z-tile) per step.
__device__ void run_l1(const KParams& p, int w2, char* zbuf, float* cst, float* biasl)
{
  const int tid = threadIdx.x;
  const int wv = tid >> 6, l = tid & 63, q = l >> 5, lr = l & 31;
  const int nh = wv & 1, kh = wv >> 1;
  const int bh = w2 & 1, sub1 = w2 >> 1;

  if (tid < 64) biasl[tid] = p.b2[tid >> 4][sub1 * 16 + (tid & 15)];

  const int c = nh * 32 + lr;
  const float* Wg = p.W2[c >> 4];
  const int un = sub1 * 16 + (c & 15);
  bf16x8 wf[16];   // this wave's K-half of W2 (z rows kh*256..+256)
#pragma unroll
  for (int s = 0; s < 16; ++s)
#pragma unroll
    for (int j = 0; j < 8; ++j) {
      int k = kh * 256 + s * 16 + q * 8 + j;
      wf[s][j] = (bf16_t)Wg[k * 256 + un];
    }
  __syncthreads();

  float cs2[2] = {0.f, 0.f};   // c-state: thread owns (b = tid>>3, units u2,u2+1)
  const int cb = tid >> 3, cu = (tid & 7) * 2;

  for (int s = 0; s < 512; ++s) {
    // merged wait: all 32 L1 peers done s-1 (h2 ready) AND all 16 L0 done s (h1 ready)
    if (wv == 0) waitcond<32, 16>(p.fl1, (u32)s, p.fl0, (u32)(s + 1), p.fl0, 0u);
    __syncthreads();

    // stage z = [h1[s] | h2[s-1]] rows bh*32..+32, all 16 loads in flight
    const u64* hp1 = (const u64*)(p.h1 + (s & (H1R - 1)) * 16384) + bh * 2048;
    const u64* hp2 = (const u64*)(p.h2 + ((s + 1) & 1) * 16384) + bh * 2048;
    u64 t1[8], t2[8];
#pragma unroll
    for (int t = 0; t < 8; ++t) t1[t] = ald64(hp1 + tid + 256 * t);
#pragma unroll
    for (int t = 0; t < 8; ++t) t2[t] = ald64(hp2 + tid + 256 * t);
#pragma unroll
    for (int t = 0; t < 8; ++t) {
      int i = tid + 256 * t, r = i >> 6, cc = i & 63;
      *(u64*)(zbuf + r * ZST + cc * 8) = t1[t];
    }
#pragma unroll
    for (int t = 0; t < 8; ++t) {
      int i = tid + 256 * t, r = i >> 6, cc = i & 63;
      *(u64*)(zbuf + r * ZST + 512 + cc * 8) = t2[t];
    }
    __syncthreads();

    floatx16 acc;
#pragma unroll
    for (int e = 0; e < 16; ++e) acc[e] = 0.f;
    const char* arow = zbuf + lr * ZST + kh * 512 + q * 16;
#pragma unroll
    for (int s2 = 0; s2 < 16; ++s2) {
      bf16x8 af = *(const bf16x8*)(arow + 32 * s2);
      acc = __builtin_amdgcn_mfma_f32_32x32x16_bf16(af, wf[s2], acc, 0, 0, 0);
    }
#pragma unroll
    for (int e = 0; e < 16; ++e) {
      int ri = (e & 3) + 8 * (e >> 2) + 4 * q;
      cst[kh * 2176 + ri * 68 + nh * 32 + lr] = acc[e];
    }
    __syncthreads();

    // cell: sum the two K-half planes + bias
    uint16_t* hout = p.h2 + (s & 1) * 16384;
    {
      float2 pf = *(float2*)&cst[cb * 68 +      cu];
      float2 pi = *(float2*)&cst[cb * 68 + 16 + cu];
      float2 pg = *(float2*)&cst[cb * 68 + 32 + cu];
      float2 po = *(float2*)&cst[cb * 68 + 48 + cu];
      float2 qf = *(float2*)&cst[2176 + cb * 68 +      cu];
      float2 qi = *(float2*)&cst[2176 + cb * 68 + 16 + cu];
      float2 qg = *(float2*)&cst[2176 + cb * 68 + 32 + cu];
      float2 qo = *(float2*)&cst[2176 + cb * 68 + 48 + cu];
      float hv[2];
#pragma unroll
      for (int j = 0; j < 2; ++j) {
        float fj = sigf((j ? pf.y + qf.y : pf.x + qf.x) + biasl[cu + j]);
        float ij = sigf((j ? pi.y + qi.y : pi.x + qi.x) + biasl[16 + cu + j]);
        float gj = tanhf_fast((j ? pg.y + qg.y : pg.x + qg.x) + biasl[32 + cu + j]);
        float oj = sigf((j ? po.y + qo.y : po.x + qo.x) + biasl[48 + cu + j]);
        float cn = fj * cs2[j] + ij * gj;
        cs2[j] = cn;
        hv[j] = oj * tanhf_fast(cn);
      }
      ast32((u32*)(hout + (bh * 32 + cb) * 256 + sub1 * 16 + cu), pack2(hv[0], hv[1]));
    }
    __syncthreads();
    if (tid == 0) ast32(&p.fl1[w2 * FP], (u32)(s + 1));
  }

  // ---- dense head part 1: 4 cols of d = relu(h2_last @ Wd + bd) -------------
  if (wv == 0) waitcond<32, 0>(p.fl1, 512u, p.fl1, 0u, p.fl1, 0u);
  __syncthreads();
  {
    const u64* hp = (const u64*)(p.h2 + 16384);   // h2[511] slab 1
    u64 tmp[16];
#pragma unroll
    for (int t = 0; t < 16; ++t) tmp[t] = ald64(hp + tid + 256 * t);
#pragma unroll
    for (int t = 0; t < 16; ++t) {
      int i = tid + 256 * t, b = i >> 6, cc = i & 63;
      *(u64*)(zbuf + b * 520 + cc * 8) = tmp[t];
    }
  }
  __syncthreads();
  {
    int b = tid >> 2, cc = w2 * 4 + (tid & 3);
    const bf16_t* hrow = (const bf16_t*)(zbuf + b * 520);
    float a = p.bd[cc];
#pragma unroll 8
    for (int k = 0; k < 256; ++k) a += (float)hrow[k] * p.Wd[k * 128 + cc];
    ast32((u32*)&p.dstage[b * 128 + cc], __builtin_bit_cast(u32, fmaxf(a, 0.f)));
  }
  __syncthreads();
  if (tid == 0) ast32(&p.fl1[w2 * FP], 513u);

  // ---- final: out = sigmoid(d @ Wout + bout), by L1 WG 0 --------------------
  if (w2 == 0) {
    if (wv == 0) waitcond<32, 0>(p.fl1, 513u, p.fl1, 0u, p.fl1, 0u);
    __syncthreads();
    if (tid < 64) {
      float a = p.bout[0];
#pragma unroll 8
      for (int cc = 0; cc < 128; ++cc) {
        u32 dv = ald32((u32*)&p.dstage[tid * 128 + cc]);
        a += __builtin_bit_cast(float, dv) * p.Wout[cc];
      }
      p.out[tid] = sigf(a);
    }
  }
}

// ---------------- Gx producers: Gx[s] = x_s @ W1x, K=300 (pad 320) -------------
__device__ void run_prod(const KParams& p, int pw, char* smem)
{
  const int tid = threadIdx.x;
  const int w = tid >> 6, l = tid & 63, q = l >> 5, lr = l & 31;
  const int mh = w & 1, chalf = w >> 1;
  const int R = p.R;

  for (int jj = 0; jj < 512 / NPROD; ++jj) {
    const int s = pw + NPROD * jj;
    if (s >= R) {  // ring throttle via producer-only mirror (off the hot fl0 lines)
      if (w == 0) waitg16(p.fl0g, (u32)(s - R + 1));
    }
    __syncthreads();
    {
      int b = tid >> 2, qq = tid & 3;
      int tokv = p.tok[b * 512 + s];
      const float4* src = (const float4*)(p.emb + (size_t)tokv * 300);
      char* dst = smem + b * 656;
      for (int j2 = qq; j2 < 75; j2 += 4) {
        float4 v = src[j2];
        *(u32*)(dst + 8 * j2)     = pack2(v.x, v.y);
        *(u32*)(dst + 8 * j2 + 4) = pack2(v.z, v.w);
      }
      for (int i = tid; i < 640; i += 256) {
        int bb = i / 10, cc2 = i % 10;
        *(u32*)(smem + bb * 656 + 600 + cc2 * 4) = 0u;
      }
    }
    __syncthreads();

    bf16x8 afr[20];
    const char* arow = smem + (mh * 32 + lr) * 656 + q * 16;
#pragma unroll
    for (int kt = 0; kt < 20; ++kt) afr[kt] = *(const bf16x8*)(arow + 32 * kt);

    float* slab = p.gx + (size_t)(s % R) * 65536u;
    for (int c2 = 0; c2 < 16; ++c2) {
      int n = (chalf * 16 + c2) * 32 + lr;
      floatx16 acc;
#pragma unroll
      for (int e = 0; e < 16; ++e) acc[e] = 0.f;
#pragma unroll
      for (int kt = 0; kt < 20; ++kt) {
        bf16x8 bf = ((const bf16x8*)p.w1bf)[(kt * 1024 + n) * 2 + q];
        acc = __builtin_amdgcn_mfma_f32_32x32x16_bf16(afr[kt], bf, acc, 0, 0, 0);
      }
#pragma unroll
      for (int e = 0; e < 16; ++e) {
        int ri = (e & 3) + 8 * (e >> 2) + 4 * q;
        ast32((u32*)(slab + (mh * 32 + ri) * 1024 + n), __builtin_bit_cast(u32, acc[e]));
      }
    }
    __syncthreads();                    // drains Gx scoped stores
    if (tid == 0) ast32(&p.pflags[s * FP], 1u);
  }
}

__global__ __launch_bounds__(256, 1) void lstm_main(KParams p)
{
  __shared__ __align__(16) char smem[64 * 656];   // L0 stage / L1 z-tile / producer buf
  __shared__ float cst[4352];                     // L0: [64][68]; L1: [2][32][68]
  __shared__ float biasl[64];
  const int wg = blockIdx.x;
  if (wg < 16)       run_l0(p, wg, smem, cst, biasl);
  else if (wg < 48)  run_l1(p, wg - 16, smem, cst, biasl);
  else               run_prod(p, wg - 48, smem);
}

// One-time: W1 x-part (rows 0..299, zero-pad to 320) -> bf16 fragment order.
__global__ void prep_w(KParams p) {
  int idx = blockIdx.x * 256 + threadIdx.x;
  if (idx >= 20 * 1024 * 16) return;
  int kk = idx & 15, n = (idx >> 4) & 1023, kt = idx >> 14;
  int k = kt * 16 + kk;
  int g = (n >> 4) & 3, su = n >> 6, u = n & 15;
  float v = (k < 300) ? p.W1[g][k * 256 + su * 16 + u] : 0.f;
  p.w1bf[idx] = (bf16_t)v;
}

// Zero h rings + all flags (ws is re-poisoned 0xAA before every launch)
__global__ void init_ws(u32* ws32) {
  int i = blockIdx.x * 256 + threadIdx.x;
  if (i < 100352) ws32[i] = 0u;   // [0, 401408): h1, h2, fl0, fl1, fl0g, pflags
}

extern "C" void kernel_launch(void* const* d_in, const int* in_sizes, int n_in,
                              void* d_out, int out_size, void* d_ws, size_t ws_size,
                              hipStream_t stream)
{
  KParams p;
  p.tok = (const int*)d_in[0];
  p.emb = (const float*)d_in[1];
  for (int g = 0; g < 4; ++g) {
    p.W1[g] = (const float*)d_in[2 + 2 * g];
    p.b1[g] = (const float*)d_in[3 + 2 * g];
    p.W2[g] = (const float*)d_in[10 + 2 * g];
    p.b2[g] = (const float*)d_in[11 + 2 * g];
  }
  p.Wd   = (const float*)d_in[18];
  p.bd   = (const float*)d_in[19];
  p.Wout = (const float*)d_in[20];
  p.bout = (const float*)d_in[21];
  p.out  = (float*)d_out;

  char* ws = (char*)d_ws;
  p.h1     = (uint16_t*)ws;               // 8 x 32768 B   -> 262144
  p.h2     = (uint16_t*)(ws + 262144);    // 2 x 32768 B   -> 327680
  p.fl0    = (u32*)(ws + 327680);         // 16 x 128 B    -> 329728
  p.fl1    = (u32*)(ws + 329728);         // 32 x 128 B    -> 333824
  p.fl0g   = (u32*)(ws + 333824);         // 16 x 128 B    -> 335872
  p.pflags = (u32*)(ws + 335872);         // 512 x 128 B   -> 401408
  p.dstage = (float*)(ws + 401408);       // 32768 B       -> 434176
  p.w1bf   = (bf16_t*)(ws + 434176);      // 655360 B      -> 1089536
  p.gx     = (float*)(ws + 1089536);      // ring: R x 262144 B

  long avail = (long)ws_size - 1089536L;
  int R = (int)(avail / 262144L);
  if (R > 64) R = 64;
  if (R < 1)  R = 1;
  p.R = R;

  hipLaunchKernelGGL(init_ws, dim3(392), dim3(256), 0, stream, (u32*)d_ws);
  hipLaunchKernelGGL(prep_w, dim3(1280), dim3(256), 0, stream, p);
  hipLaunchKernelGGL(lstm_main, dim3(16 + 32 + NPROD), dim3(256), 0, stream, p);
}